// Round 6
// baseline (2722.847 us; speedup 1.0000x reference)
//
#include <hip/hip_runtime.h>
#include <hip/hip_bf16.h>

// Fused LIF, R5: per block = (one b) x (64-h chunk). grid = 512 = 2 blocks/CU
// (R4's 256 blocks = 1 block/CU exposed every barrier; VALUBusy 44%).
// Per chunk of 256 t: fp32 tile GEMM (256t x 64h x 512K, BK=16, 8x8 frag,
// v_pk_fma_f32), LDS double-buffered with ONE barrier per K-step; then the
// 256-step scan runs in-block (u,s carried in LDS), while the NEXT chunk's
// first tile loads are already in flight (issued at the last K-step).
// Accumulation order per (t,h) identical to R2/R4 -> absmax 0 expected.

#define ALPHA_LO_F 0.8187307530779818f   // exp(-1/5)
#define ALPHA_HI_F 0.9607894391523232f   // exp(-1/25)

typedef float v2f __attribute__((ext_vector_type(2)));

#define T_DIM 1024
#define K_DIM 512
#define H_DIM 512
#define CT    256        // t-rows per chunk
#define CH    64         // h per block
#define NCHK  (T_DIM / CT)
#define BK    16
#define APAD  260        // As row stride: kq*APAD banks alternate 0/16 -> 2-way writes (free)
#define BPAD  68         // Bs row stride: same property

__global__ __launch_bounds__(256, 2) void lif_fused(
    const float* __restrict__ x,      // [B, T, K]
    const float* __restrict__ W,      // [H, K]
    const float* __restrict__ alpha,  // [H]
    const float* __restrict__ u0,     // [B, H]
    const float* __restrict__ s0,     // [B, H]
    float* __restrict__ out)          // [B, T, H]
{
    __shared__ float As[2][BK][APAD];   // 33.3 KB
    __shared__ float Bs[2][BK][BPAD];   //  8.7 KB
    __shared__ float u_s[CH], s_s[CH], al_s[CH];

    const int tid = threadIdx.x;
    const int b   = blockIdx.x & 63;      // same-b blocks are 64 apart -> same XCD (%8)
    const int hc  = blockIdx.x >> 6;      // 0..7
    const int h0  = hc * CH;

    if (tid < CH) {
        const int h = h0 + tid;
        float a = alpha[h];
        al_s[tid] = fminf(fmaxf(a, ALPHA_LO_F), ALPHA_HI_F);
        u_s[tid] = u0[(size_t)b * H_DIM + h];
        s_s[tid] = s0[(size_t)b * H_DIM + h];
    }

    const int tm = tid >> 3;              // 0..31 : t-row group (8 rows each)
    const int tn = tid & 7;               // 0..7  : h-col group (8 cols each)

    // staging maps
    const int arow = tid >> 2;            // base row for A loads (0..63, +64 per r)
    const int akq  = (tid & 3) * 4;
    const int brow = tid >> 2;            // 0..63
    const int bkq  = (tid & 3) * 4;

    const float* xb = x + (size_t)b * T_DIM * K_DIM;
    const float* Wc = W + (size_t)h0 * K_DIM;

    float4 aR[4]; float4 bR;

    // initial tile: chunk 0, k0 = 0
    {
        #pragma unroll
        for (int r = 0; r < 4; ++r)
            aR[r] = *(const float4*)(xb + (size_t)(arow + r * 64) * K_DIM + akq);
        bR = *(const float4*)(Wc + (size_t)brow * K_DIM + bkq);
    }

    __syncthreads();   // covers u_s/s_s init

    for (int c = 0; c < NCHK; ++c) {
        const int t0 = c * CT;

        // write staged tile -> buf 0
        #pragma unroll
        for (int r = 0; r < 4; ++r) {
            const int row = arow + r * 64;
            As[0][akq + 0][row] = aR[r].x;  As[0][akq + 1][row] = aR[r].y;
            As[0][akq + 2][row] = aR[r].z;  As[0][akq + 3][row] = aR[r].w;
        }
        Bs[0][bkq + 0][brow] = bR.x;  Bs[0][bkq + 1][brow] = bR.y;
        Bs[0][bkq + 2][brow] = bR.z;  Bs[0][bkq + 3][brow] = bR.w;
        __syncthreads();

        v2f acc[8][4] = {};

        for (int kt = 0; kt < K_DIM / BK; ++kt) {
            const int cur = kt & 1;

            // issue next global loads: next K-tile, or next chunk's first tile
            if (kt < K_DIM / BK - 1) {
                const int k0n = (kt + 1) * BK;
                #pragma unroll
                for (int r = 0; r < 4; ++r)
                    aR[r] = *(const float4*)(xb + (size_t)(t0 + arow + r * 64) * K_DIM + k0n + akq);
                bR = *(const float4*)(Wc + (size_t)brow * K_DIM + k0n + bkq);
            } else if (c + 1 < NCHK) {
                const int t0n = (c + 1) * CT;
                #pragma unroll
                for (int r = 0; r < 4; ++r)
                    aR[r] = *(const float4*)(xb + (size_t)(t0n + arow + r * 64) * K_DIM + akq);
                bR = *(const float4*)(Wc + (size_t)brow * K_DIM + bkq);
            }

            // compute on buf[cur]
            #pragma unroll
            for (int k = 0; k < BK; ++k) {
                const float* Ak = &As[cur][k][tm * 8];
                const float* Bk = &Bs[cur][k][tn * 8];
                float4 a0 = *(const float4*)(Ak);
                float4 a1 = *(const float4*)(Ak + 4);
                float4 b0 = *(const float4*)(Bk);
                float4 b1 = *(const float4*)(Bk + 4);
                v2f bb[4];
                bb[0] = (v2f){b0.x, b0.y};  bb[1] = (v2f){b0.z, b0.w};
                bb[2] = (v2f){b1.x, b1.y};  bb[3] = (v2f){b1.z, b1.w};
                float a[8] = {a0.x, a0.y, a0.z, a0.w, a1.x, a1.y, a1.z, a1.w};
                #pragma unroll
                for (int i = 0; i < 8; ++i) {
                    v2f ai = (v2f){a[i], a[i]};
                    #pragma unroll
                    for (int jv = 0; jv < 4; ++jv)
                        acc[i][jv] = __builtin_elementwise_fma(ai, bb[jv], acc[i][jv]);
                }
            }

            // write next tile into the other buffer (not on the last K-step:
            // the cross-chunk tile is written at the top of the next chunk,
            // keeping those loads in flight across the scan phase)
            if (kt < K_DIM / BK - 1) {
                const int nb = cur ^ 1;
                #pragma unroll
                for (int r = 0; r < 4; ++r) {
                    const int row = arow + r * 64;
                    As[nb][akq + 0][row] = aR[r].x;  As[nb][akq + 1][row] = aR[r].y;
                    As[nb][akq + 2][row] = aR[r].z;  As[nb][akq + 3][row] = aR[r].w;
                }
                Bs[nb][bkq + 0][brow] = bR.x;  Bs[nb][bkq + 1][brow] = bR.y;
                Bs[nb][bkq + 2][brow] = bR.z;  Bs[nb][bkq + 3][brow] = bR.w;
            }
            __syncthreads();
        }

        // ============ scan phase: 32 sequential stages over this chunk ======
        for (int stage = 0; stage < 32; ++stage) {
            if (tm == stage) {
                const int hb = tn * 8;
                float u[8], s[8], av[8], om[8];
                #pragma unroll
                for (int j = 0; j < 8; ++j) {
                    u[j]  = u_s[hb + j];
                    s[j]  = s_s[hb + j];
                    av[j] = al_s[hb + j];
                    om[j] = 1.0f - av[j];
                }
                #pragma unroll
                for (int i = 0; i < 8; ++i) {
                    float wx[8] = {acc[i][0].x, acc[i][0].y, acc[i][1].x, acc[i][1].y,
                                   acc[i][2].x, acc[i][2].y, acc[i][3].x, acc[i][3].y};
                    #pragma unroll
                    for (int j = 0; j < 8; ++j) {
                        u[j] = av[j] * (u[j] - s[j]) + om[j] * wx[j];
                        s[j] = (u[j] - 1.0f > 0.0f) ? 1.0f : 0.0f;
                    }
                    const int t = t0 + stage * 8 + i;
                    float* orow = out + ((size_t)b * T_DIM + t) * H_DIM + h0 + hb;
                    *(float4*)(orow)     = make_float4(s[0], s[1], s[2], s[3]);
                    *(float4*)(orow + 4) = make_float4(s[4], s[5], s[6], s[7]);
                }
                #pragma unroll
                for (int j = 0; j < 8; ++j) {
                    u_s[hb + j] = u[j];
                    s_s[hb + j] = s[j];
                }
            }
            __syncthreads();
        }
    }
}

extern "C" void kernel_launch(void* const* d_in, const int* in_sizes, int n_in,
                              void* d_out, int out_size, void* d_ws, size_t ws_size,
                              hipStream_t stream) {
    const float* x     = (const float*)d_in[0];   // [B, T, I]
    const float* W     = (const float*)d_in[1];   // [H, I]
    const float* alpha = (const float*)d_in[2];   // [H]
    const float* u0    = (const float*)d_in[3];   // [B, H]
    const float* s0    = (const float*)d_in[4];   // [B, H]
    float* out = (float*)d_out;                   // [B, T, H]

    const int H = in_sizes[2];                    // 512
    const int B = in_sizes[3] / H;                // 64
    const int grid = (H_DIM / CH) * B;            // 8 * 64 = 512 blocks

    lif_fused<<<grid, 256, 0, stream>>>(x, W, alpha, u0, s0, out);
}

// Round 7
// 735.917 us; speedup vs baseline: 3.6999x; 3.6999x over previous
//
#include <hip/hip_runtime.h>
#include <hip/hip_bf16.h>

// Fused LIF, R6: per block = (one b) x (64-h chunk), grid 512 = 2 blocks/CU.
// Per chunk of 256 t: fp32 tile GEMM (256t x 64h x 512K, BK=16, 8x8 frag,
// v_pk_fma_f32) with R4's SIMPLE two-barrier staging (transient regs -> LDS;
// R5's register-carried double-buffer spilled 11 GB of scratch), then the
// in-block 32-stage scan. Co-resident block's GEMM overlaps barriers/scan.
// Accumulation order per (t,h) identical to R2/R4 -> absmax 0 expected.

#define ALPHA_LO_F 0.8187307530779818f   // exp(-1/5)
#define ALPHA_HI_F 0.9607894391523232f   // exp(-1/25)

typedef float v2f __attribute__((ext_vector_type(2)));

#define T_DIM 1024
#define K_DIM 512
#define H_DIM 512
#define CT    256        // t-rows per chunk
#define CH    64         // h per block
#define NCHK  (T_DIM / CT)
#define BK    16
#define APAD  260        // As row stride: scatter writes land 2-way/bank (free)
#define BPAD  68         // Bs row stride: same property

__global__ __launch_bounds__(256, 2) void lif_fused(
    const float* __restrict__ x,      // [B, T, K]
    const float* __restrict__ W,      // [H, K]
    const float* __restrict__ alpha,  // [H]
    const float* __restrict__ u0,     // [B, H]
    const float* __restrict__ s0,     // [B, H]
    float* __restrict__ out)          // [B, T, H]
{
    __shared__ float As[BK][APAD];    // 16.6 KB
    __shared__ float Bs[BK][BPAD];    //  4.4 KB
    __shared__ float u_s[CH], s_s[CH], al_s[CH];

    const int tid = threadIdx.x;
    const int b   = blockIdx.x & 63;      // same-b blocks are 64 apart -> same XCD (%8)
    const int hc  = blockIdx.x >> 6;      // 0..7
    const int h0  = hc * CH;

    if (tid < CH) {
        const int h = h0 + tid;
        float a = alpha[h];
        al_s[tid] = fminf(fmaxf(a, ALPHA_LO_F), ALPHA_HI_F);
        u_s[tid] = u0[(size_t)b * H_DIM + h];
        s_s[tid] = s0[(size_t)b * H_DIM + h];
    }

    const int tm = tid >> 3;              // 0..31 : t-row group (8 rows each)
    const int tn = tid & 7;               // 0..7  : h-col group (8 cols each)

    // staging maps (transient): A = 1024 float4 (4/thread), B = 256 float4 (1/thread)
    const int arow = tid >> 2;            // 0..63, +64 per r
    const int akq  = (tid & 3) * 4;
    const int brow = tid >> 2;            // 0..63
    const int bkq  = (tid & 3) * 4;

    const float* xb = x + (size_t)b * T_DIM * K_DIM;
    const float* Wc = W + (size_t)h0 * K_DIM;

    __syncthreads();   // covers u_s/s_s init

    for (int c = 0; c < NCHK; ++c) {
        const int t0 = c * CT;

        v2f acc[8][4] = {};

        for (int k0 = 0; k0 < K_DIM; k0 += BK) {
            // ---- stage tiles (load -> LDS immediately; regs transient) ----
            #pragma unroll
            for (int r = 0; r < 4; ++r) {
                const int row = arow + r * 64;
                float4 v = *(const float4*)(xb + (size_t)(t0 + row) * K_DIM + k0 + akq);
                As[akq + 0][row] = v.x;  As[akq + 1][row] = v.y;
                As[akq + 2][row] = v.z;  As[akq + 3][row] = v.w;
            }
            {
                float4 v = *(const float4*)(Wc + (size_t)brow * K_DIM + k0 + bkq);
                Bs[bkq + 0][brow] = v.x;  Bs[bkq + 1][brow] = v.y;
                Bs[bkq + 2][brow] = v.z;  Bs[bkq + 3][brow] = v.w;
            }
            __syncthreads();

            #pragma unroll
            for (int k = 0; k < BK; ++k) {
                const float* Ak = &As[k][tm * 8];
                const float* Bk = &Bs[k][tn * 8];
                float4 a0 = *(const float4*)(Ak);
                float4 a1 = *(const float4*)(Ak + 4);
                float4 b0 = *(const float4*)(Bk);
                float4 b1 = *(const float4*)(Bk + 4);
                v2f bb[4];
                bb[0] = (v2f){b0.x, b0.y};  bb[1] = (v2f){b0.z, b0.w};
                bb[2] = (v2f){b1.x, b1.y};  bb[3] = (v2f){b1.z, b1.w};
                float a[8] = {a0.x, a0.y, a0.z, a0.w, a1.x, a1.y, a1.z, a1.w};
                #pragma unroll
                for (int i = 0; i < 8; ++i) {
                    v2f ai = (v2f){a[i], a[i]};
                    #pragma unroll
                    for (int jv = 0; jv < 4; ++jv)
                        acc[i][jv] = __builtin_elementwise_fma(ai, bb[jv], acc[i][jv]);
                }
            }
            __syncthreads();
        }

        // ---- scan phase: 32 sequential stages over this chunk ----
        for (int stage = 0; stage < 32; ++stage) {
            if (tm == stage) {
                const int hb = tn * 8;
                float u[8], s[8], av[8], om[8];
                #pragma unroll
                for (int j = 0; j < 8; ++j) {
                    u[j]  = u_s[hb + j];
                    s[j]  = s_s[hb + j];
                    av[j] = al_s[hb + j];
                    om[j] = 1.0f - av[j];
                }
                #pragma unroll
                for (int i = 0; i < 8; ++i) {
                    float wx[8] = {acc[i][0].x, acc[i][0].y, acc[i][1].x, acc[i][1].y,
                                   acc[i][2].x, acc[i][2].y, acc[i][3].x, acc[i][3].y};
                    #pragma unroll
                    for (int j = 0; j < 8; ++j) {
                        u[j] = av[j] * (u[j] - s[j]) + om[j] * wx[j];
                        s[j] = (u[j] - 1.0f > 0.0f) ? 1.0f : 0.0f;
                    }
                    const int t = t0 + stage * 8 + i;
                    float* orow = out + ((size_t)b * T_DIM + t) * H_DIM + h0 + hb;
                    *(float4*)(orow)     = make_float4(s[0], s[1], s[2], s[3]);
                    *(float4*)(orow + 4) = make_float4(s[4], s[5], s[6], s[7]);
                }
                #pragma unroll
                for (int j = 0; j < 8; ++j) {
                    u_s[hb + j] = u[j];
                    s_s[hb + j] = s[j];
                }
            }
            __syncthreads();
        }
    }
}

extern "C" void kernel_launch(void* const* d_in, const int* in_sizes, int n_in,
                              void* d_out, int out_size, void* d_ws, size_t ws_size,
                              hipStream_t stream) {
    const float* x     = (const float*)d_in[0];   // [B, T, I]
    const float* W     = (const float*)d_in[1];   // [H, I]
    const float* alpha = (const float*)d_in[2];   // [H]
    const float* u0    = (const float*)d_in[3];   // [B, H]
    const float* s0    = (const float*)d_in[4];   // [B, H]
    float* out = (float*)d_out;                   // [B, T, H]

    const int H = in_sizes[2];                    // 512
    const int B = in_sizes[3] / H;                // 64
    const int grid = (H_DIM / CH) * B;            // 8 * 64 = 512 blocks

    lif_fused<<<grid, 256, 0, stream>>>(x, W, alpha, u0, s0, out);
}

// Round 8
// 716.805 us; speedup vs baseline: 3.7986x; 1.0267x over previous
//
#include <hip/hip_runtime.h>
#include <hip/hip_bf16.h>

// Fused LIF, R7: R6 structure, but 512-thread blocks (8 waves) so 2 blocks/CU
// = 16 waves/CU = 4 waves/SIMD (R6's 256-thr blocks gave 2/SIMD -> one block's
// barrier/scan phase left the SIMD half-idle -> VALUBusy 46%).
// Per block = (one b) x (64-h chunk); 2 chunks of 512 t. Per chunk: fp32 tile
// GEMM (512t x 64h x 512K, BK=16, 8x8 frag/thread, v_pk_fma_f32) with simple
// two-barrier staging (transient regs; R5's carried double-buffer spilled),
// then the in-block 64-stage scan ladder. Same per-(t,h) accumulation order
// as R2/R4/R6 -> absmax 0 expected.

#define ALPHA_LO_F 0.8187307530779818f   // exp(-1/5)
#define ALPHA_HI_F 0.9607894391523232f   // exp(-1/25)

typedef float v2f __attribute__((ext_vector_type(2)));

#define T_DIM 1024
#define K_DIM 512
#define H_DIM 512
#define CT    512        // t-rows per chunk
#define CH    64         // h per block
#define NCHK  (T_DIM / CT)
#define BK    16
#define APAD  516        // As row stride (CT+4): scatter writes 2-way/bank (free)
#define BPAD  68         // Bs row stride

__global__ __launch_bounds__(512, 4) void lif_fused(
    const float* __restrict__ x,      // [B, T, K]
    const float* __restrict__ W,      // [H, K]
    const float* __restrict__ alpha,  // [H]
    const float* __restrict__ u0,     // [B, H]
    const float* __restrict__ s0,     // [B, H]
    float* __restrict__ out)          // [B, T, H]
{
    __shared__ float As[BK][APAD];    // 33.0 KB
    __shared__ float Bs[BK][BPAD];    //  4.4 KB
    __shared__ float u_s[CH], s_s[CH], al_s[CH];

    const int tid = threadIdx.x;
    const int b   = blockIdx.x & 63;      // same-b blocks are 64 apart -> same XCD (%8)
    const int hc  = blockIdx.x >> 6;      // 0..7
    const int h0  = hc * CH;

    if (tid < CH) {
        const int h = h0 + tid;
        float a = alpha[h];
        al_s[tid] = fminf(fmaxf(a, ALPHA_LO_F), ALPHA_HI_F);
        u_s[tid] = u0[(size_t)b * H_DIM + h];
        s_s[tid] = s0[(size_t)b * H_DIM + h];
    }

    const int tm = tid >> 3;              // 0..63 : t-row group (8 rows each)
    const int tn = tid & 7;               // 0..7  : h-col group (8 cols each)

    // staging maps (transient regs). A tile: 512 rows x 16 k = 2048 float4,
    // 4 per thread. B tile: 64 rows x 16 k = 256 float4, threads 0..255.
    const int arow = tid >> 2;            // 0..127, +128 per r
    const int akq  = (tid & 3) * 4;

    const float* xb = x + (size_t)b * T_DIM * K_DIM;
    const float* Wc = W + (size_t)h0 * K_DIM;

    __syncthreads();   // covers u_s/s_s init

    for (int c = 0; c < NCHK; ++c) {
        const int t0 = c * CT;

        v2f acc[8][4] = {};

        for (int k0 = 0; k0 < K_DIM; k0 += BK) {
            // ---- stage tiles (load -> LDS immediately; regs transient) ----
            #pragma unroll
            for (int r = 0; r < 4; ++r) {
                const int row = arow + r * 128;
                float4 v = *(const float4*)(xb + (size_t)(t0 + row) * K_DIM + k0 + akq);
                As[akq + 0][row] = v.x;  As[akq + 1][row] = v.y;
                As[akq + 2][row] = v.z;  As[akq + 3][row] = v.w;
            }
            if (tid < 256) {
                const int brow = tid >> 2;          // 0..63
                const int bkq  = (tid & 3) * 4;
                float4 v = *(const float4*)(Wc + (size_t)brow * K_DIM + k0 + bkq);
                Bs[bkq + 0][brow] = v.x;  Bs[bkq + 1][brow] = v.y;
                Bs[bkq + 2][brow] = v.z;  Bs[bkq + 3][brow] = v.w;
            }
            __syncthreads();

            #pragma unroll
            for (int k = 0; k < BK; ++k) {
                const float* Ak = &As[k][tm * 8];
                const float* Bk = &Bs[k][tn * 8];
                float4 a0 = *(const float4*)(Ak);
                float4 a1 = *(const float4*)(Ak + 4);
                float4 b0 = *(const float4*)(Bk);
                float4 b1 = *(const float4*)(Bk + 4);
                v2f bb[4];
                bb[0] = (v2f){b0.x, b0.y};  bb[1] = (v2f){b0.z, b0.w};
                bb[2] = (v2f){b1.x, b1.y};  bb[3] = (v2f){b1.z, b1.w};
                float a[8] = {a0.x, a0.y, a0.z, a0.w, a1.x, a1.y, a1.z, a1.w};
                #pragma unroll
                for (int i = 0; i < 8; ++i) {
                    v2f ai = (v2f){a[i], a[i]};
                    #pragma unroll
                    for (int jv = 0; jv < 4; ++jv)
                        acc[i][jv] = __builtin_elementwise_fma(ai, bb[jv], acc[i][jv]);
                }
            }
            __syncthreads();
        }

        // ---- scan phase: 64 sequential stages over this chunk ----
        for (int stage = 0; stage < CT / 8; ++stage) {
            if (tm == stage) {
                const int hb = tn * 8;
                float u[8], s[8], av[8], om[8];
                #pragma unroll
                for (int j = 0; j < 8; ++j) {
                    u[j]  = u_s[hb + j];
                    s[j]  = s_s[hb + j];
                    av[j] = al_s[hb + j];
                    om[j] = 1.0f - av[j];
                }
                #pragma unroll
                for (int i = 0; i < 8; ++i) {
                    float wx[8] = {acc[i][0].x, acc[i][0].y, acc[i][1].x, acc[i][1].y,
                                   acc[i][2].x, acc[i][2].y, acc[i][3].x, acc[i][3].y};
                    #pragma unroll
                    for (int j = 0; j < 8; ++j) {
                        u[j] = av[j] * (u[j] - s[j]) + om[j] * wx[j];
                        s[j] = (u[j] - 1.0f > 0.0f) ? 1.0f : 0.0f;
                    }
                    const int t = t0 + stage * 8 + i;
                    float* orow = out + ((size_t)b * T_DIM + t) * H_DIM + h0 + hb;
                    *(float4*)(orow)     = make_float4(s[0], s[1], s[2], s[3]);
                    *(float4*)(orow + 4) = make_float4(s[4], s[5], s[6], s[7]);
                }
                #pragma unroll
                for (int j = 0; j < 8; ++j) {
                    u_s[hb + j] = u[j];
                    s_s[hb + j] = s[j];
                }
            }
            __syncthreads();
        }
    }
}

extern "C" void kernel_launch(void* const* d_in, const int* in_sizes, int n_in,
                              void* d_out, int out_size, void* d_ws, size_t ws_size,
                              hipStream_t stream) {
    const float* x     = (const float*)d_in[0];   // [B, T, I]
    const float* W     = (const float*)d_in[1];   // [H, I]
    const float* alpha = (const float*)d_in[2];   // [H]
    const float* u0    = (const float*)d_in[3];   // [B, H]
    const float* s0    = (const float*)d_in[4];   // [B, H]
    float* out = (float*)d_out;                   // [B, T, H]

    const int H = in_sizes[2];                    // 512
    const int B = in_sizes[3] / H;                // 64
    const int grid = (H_DIM / CH) * B;            // 8 * 64 = 512 blocks

    lif_fused<<<grid, 512, 0, stream>>>(x, W, alpha, u0, s0, out);
}